// Round 5
// baseline (276.175 us; speedup 1.0000x reference)
//
#include <hip/hip_runtime.h>
#include <math.h>

// Problem constants (B=8, N=36, D=64)
#define NB    8
#define NNODE 36
#define NN2   1296     // 36*36
#define ND    64
#define NC    72       // 2*N constraints
#define KDIAG 1225.0   // (N-1)^2
#define EPSK  1e-5
#define CGMAX 32
#define PERTHREAD 6    // ceil(1296/256)

// ---------------------------------------------------------------------------
// Block-wide fp64 sum reduction (256 threads = 4 waves of 64)
// ---------------------------------------------------------------------------
__device__ __forceinline__ double blk_reduce(double v, double* red, double* out) {
#pragma unroll
  for (int off = 32; off > 0; off >>= 1) v += __shfl_down(v, off);
  if ((threadIdx.x & 63) == 0) red[threadIdx.x >> 6] = v;
  __syncthreads();
  if (threadIdx.x == 0) *out = red[0] + red[1] + red[2] + red[3];
  __syncthreads();
  return *out;
}

// ---------------------------------------------------------------------------
// Kernel 1: normalize over node axis, linear (W_cg,b_cg), relu, then
// PT[b][t][s] = Mp[b][s][t] = h1[b,s,:]·h2[b,t,:]
// PT flat (t-major) is simultaneously the KKT primal rhs Mpp.
// ---------------------------------------------------------------------------
__global__ __launch_bounds__(256) void k_feat_p(const float* __restrict__ emb1,
                                                const float* __restrict__ emb2,
                                                const float* __restrict__ Wcg,
                                                const float* __restrict__ bcg,
                                                float* __restrict__ PT) {
  const int b = blockIdx.x;
  __shared__ float e1[NNODE * ND], e2[NNODE * ND];
  __shared__ float h1[NNODE * ND], h2[NNODE * ND];
  __shared__ float Ws[ND * ND];
  __shared__ float nrm1[ND], nrm2[ND];
  const int tid = threadIdx.x;

  for (int i = tid; i < NNODE * ND; i += 256) {
    e1[i] = emb1[b * NNODE * ND + i];
    e2[i] = emb2[b * NNODE * ND + i];
  }
  for (int i = tid; i < ND * ND; i += 256) Ws[i] = Wcg[i];
  __syncthreads();

  // per-(b,d) L2 norm over the 36 nodes, clipped at 1e-12 (ref: clip(norm,1e-12))
  if (tid < ND) {
    float s = 0.f;
    for (int n = 0; n < NNODE; ++n) { float v = e1[n * ND + tid]; s += v * v; }
    nrm1[tid] = fmaxf(sqrtf(s), 1e-12f);
  } else if (tid < 2 * ND) {
    int d = tid - ND;
    float s = 0.f;
    for (int n = 0; n < NNODE; ++n) { float v = e2[n * ND + d]; s += v * v; }
    nrm2[d] = fmaxf(sqrtf(s), 1e-12f);
  }
  __syncthreads();

  for (int i = tid; i < NNODE * ND; i += 256) {
    int d = i & (ND - 1);
    e1[i] /= nrm1[d];
    e2[i] /= nrm2[d];
  }
  __syncthreads();

  // h[n][i] = relu( sum_d e[n][d] * W[i][d] + b[i] )
  for (int o = tid; o < NNODE * ND; o += 256) {
    int n = o >> 6, i = o & (ND - 1);
    float a1 = bcg[i], a2 = bcg[i];
    for (int d = 0; d < ND; ++d) {
      float w = Ws[i * ND + d];
      a1 += e1[n * ND + d] * w;
      a2 += e2[n * ND + d] * w;
    }
    h1[o] = fmaxf(a1, 0.f);
    h2[o] = fmaxf(a2, 0.f);
  }
  __syncthreads();

  // PT[t][s] = sum_d h1[s][d]*h2[t][d]
  for (int o = tid; o < NN2; o += 256) {
    int t = o / NNODE, s = o % NNODE;
    float a = 0.f;
    for (int d = 0; d < ND; ++d) a += h1[s * ND + d] * h2[t * ND + d];
    PT[b * NN2 + o] = a;
  }
}

// ---------------------------------------------------------------------------
// Kernel 2: one workgroup per (batch, rhs) — fp64 CG on Q = 1225*I - M,
// with O(n^2) structured matvec (inclusion-exclusion over the delta masks):
//   (Mx)[t][s] = 0.5*( PT[t][s]*(tot - R[t] - C[s] + x[t][s])
//                     + (Wtot - WR[t] - WC[s] + PT[t][s]*x[t][s]) )
//   where W = PT .* x,  R/C = row/col sums of x (row = first flat index).
// Only pv (cross-thread row/col sums) and pt live in LDS; x, r, ap are
// per-thread register arrays over the fixed partition i = tid + 256k.
// rid==72 -> rhs = PT (primal rhs), store fp64 into Y
// rid<36  -> rhs = (second idx == rid) indicator (A1 row);
// rid in [36,72) -> (first idx == rid-36) indicator (A2 row).
// ---------------------------------------------------------------------------
__global__ __launch_bounds__(256) void k_cg(const float* __restrict__ PT,
                                            float* __restrict__ Z,
                                            double* __restrict__ Y) {
  const int b = blockIdx.x / 73;
  const int rid = blockIdx.x % 73;
  const int tid = threadIdx.x;

  __shared__ float pt[NN2];
  __shared__ double pv[NN2];
  __shared__ double R[NNODE], C[NNODE], WR[NNODE], WC[NNODE];
  __shared__ double totW[2];  // [0]=tot(pv), [1]=tot(pt.*pv)
  __shared__ double red[4], s_pap, s_rr;

  double xl[PERTHREAD], rl[PERTHREAD], al[PERTHREAD];

  for (int i = tid; i < NN2; i += 256) pt[i] = PT[b * NN2 + i];
  __syncthreads();

#pragma unroll
  for (int k = 0; k < PERTHREAD; ++k) {
    int i = tid + 256 * k;
    if (i >= NN2) break;
    int t = i / NNODE, s = i % NNODE;
    double rhs;
    if (rid == 72)      rhs = (double)pt[i];
    else if (rid < 36)  rhs = (s == rid) ? 1.0 : 0.0;
    else                rhs = (t == rid - 36) ? 1.0 : 0.0;
    xl[k] = 0.0; rl[k] = rhs; pv[i] = rhs;
  }
  __syncthreads();

  double loc = 0.0;
#pragma unroll
  for (int k = 0; k < PERTHREAD; ++k) {
    int i = tid + 256 * k;
    if (i < NN2) loc += rl[k] * rl[k];
  }
  double rr = blk_reduce(loc, red, &s_rr);
  const double rr0 = rr;

  for (int it = 0; it < CGMAX; ++it) {
    // ---- row/col sums of pv and W = pt.*pv ----
    if (tid < NNODE) {
      double r0 = 0.0, wr0 = 0.0;
      for (int s = 0; s < NNODE; ++s) {
        double v = pv[tid * NNODE + s];
        r0 += v; wr0 += (double)pt[tid * NNODE + s] * v;
      }
      R[tid] = r0; WR[tid] = wr0;
    } else if (tid < 2 * NNODE) {
      int s = tid - NNODE;
      double c0 = 0.0, wc0 = 0.0;
      for (int t = 0; t < NNODE; ++t) {
        double v = pv[t * NNODE + s];
        c0 += v; wc0 += (double)pt[t * NNODE + s] * v;
      }
      C[s] = c0; WC[s] = wc0;
    }
    __syncthreads();
    if (tid == 0) {
      double tt = 0.0, wt = 0.0;
      for (int t = 0; t < NNODE; ++t) { tt += R[t]; wt += WR[t]; }
      totW[0] = tt; totW[1] = wt;
    }
    __syncthreads();

    // ---- ap = Q*pv (registers), pap = pv.ap ----
    double locpap = 0.0;
#pragma unroll
    for (int k = 0; k < PERTHREAD; ++k) {
      int i = tid + 256 * k;
      if (i >= NN2) break;
      int t = i / NNODE, s = i % NNODE;
      double pval = pv[i], ptv = (double)pt[i];
      double sig1 = totW[0] - R[t] - C[s] + pval;
      double sig2 = totW[1] - WR[t] - WC[s] + ptv * pval;
      double q = KDIAG * pval - 0.5 * (ptv * sig1 + sig2);
      al[k] = q;
      locpap += pval * q;
    }
    double pap = blk_reduce(locpap, red, &s_pap);
    double alpha = rr / pap;

    double locrr = 0.0;
#pragma unroll
    for (int k = 0; k < PERTHREAD; ++k) {
      int i = tid + 256 * k;
      if (i >= NN2) break;
      xl[k] += alpha * pv[i];
      double rn = rl[k] - alpha * al[k];
      rl[k] = rn;
      locrr += rn * rn;
    }
    double rrn = blk_reduce(locrr, red, &s_rr);
    double beta = rrn / rr;
    rr = rrn;
    // rel. residual 1e-9: plenty vs the reference's own fp32-LU noise, and
    // S-assembly error stays ~1e-10 << eps pivot 1e-5. Exit is block-uniform.
    if (rr < 1e-18 * rr0 || rr < 1e-30) break;
#pragma unroll
    for (int k = 0; k < PERTHREAD; ++k) {
      int i = tid + 256 * k;
      if (i < NN2) pv[i] = rl[k] + beta * pv[i];
    }
    __syncthreads();
  }

  if (rid == 72) {
#pragma unroll
    for (int k = 0; k < PERTHREAD; ++k) {
      int i = tid + 256 * k;
      if (i < NN2) Y[b * NN2 + i] = xl[k];
    }
  } else {
#pragma unroll
    for (int k = 0; k < PERTHREAD; ++k) {
      int i = tid + 256 * k;
      if (i < NN2) Z[(b * NC + rid) * NN2 + i] = (float)xl[k];
    }
  }
}

// ---------------------------------------------------------------------------
// Kernel 3 (merged Schur + output): per batch,
//   S = A*Z + eps*I (72x72), rhs = A*y - 1, fp64 Cholesky -> lambda,
//   x = y - Z*lambda, clamp [0,1],
//   out[b][i][j] = softmax_j(1000 * x[j][i])
// A applied to vector v (flat [t][s]): row i<36 -> sum over s==i,
// row i>=36 -> sum over t==i-36.
// ---------------------------------------------------------------------------
__global__ __launch_bounds__(256) void k_solve_out(const float* __restrict__ Z,
                                                   const double* __restrict__ Y,
                                                   float* __restrict__ out) {
  const int b = blockIdx.x;
  const int tid = threadIdx.x;
  __shared__ double S[NC * NC];
  __shared__ double lam[NC];
  __shared__ float xm[NN2];

  const float* Zb = Z + (size_t)b * NC * NN2;
  const double* yb = Y + (size_t)b * NN2;

  for (int o = tid; o < NC * NC; o += 256) {
    int i = o / NC, j = o % NC;
    const float* z = Zb + j * NN2;
    double acc = 0.0;
    if (i < 36) { for (int t = 0; t < NNODE; ++t) acc += (double)z[t * NNODE + i]; }
    else        { int t = i - 36; for (int s = 0; s < NNODE; ++s) acc += (double)z[t * NNODE + s]; }
    if (i == j) acc += EPSK;
    S[o] = acc;
  }
  if (tid < NC) {
    double acc = 0.0;
    if (tid < 36) { for (int t = 0; t < NNODE; ++t) acc += yb[t * NNODE + tid]; }
    else          { int t = tid - 36; for (int s = 0; s < NNODE; ++s) acc += yb[t * NNODE + s]; }
    lam[tid] = acc - 1.0;
  }
  __syncthreads();

  // Cholesky (lower), in place
  for (int j = 0; j < NC; ++j) {
    if (tid == 0) {
      double d = S[j * NC + j];
      for (int k = 0; k < j; ++k) d -= S[j * NC + k] * S[j * NC + k];
      S[j * NC + j] = sqrt(d);
    }
    __syncthreads();
    for (int i = j + 1 + tid; i < NC; i += 256) {
      double v = S[i * NC + j];
      for (int k = 0; k < j; ++k) v -= S[i * NC + k] * S[j * NC + k];
      S[i * NC + j] = v / S[j * NC + j];
    }
    __syncthreads();
  }
  // forward: L u = rhs
  for (int j = 0; j < NC; ++j) {
    if (tid == 0) lam[j] = lam[j] / S[j * NC + j];
    __syncthreads();
    for (int i = j + 1 + tid; i < NC; i += 256) lam[i] -= S[i * NC + j] * lam[j];
    __syncthreads();
  }
  // backward: L^T lam = u
  for (int j = NC - 1; j >= 0; --j) {
    if (tid == 0) lam[j] = lam[j] / S[j * NC + j];
    __syncthreads();
    if (tid < j) lam[tid] -= S[j * NC + tid] * lam[j];
    __syncthreads();
  }
  __syncthreads();

  // x = y - Z*lambda, clamp to [0,1]; xm stored flat (first-index-major)
  for (int i = tid; i < NN2; i += 256) {
    double acc = yb[i];
    for (int j = 0; j < NC; ++j) acc -= (double)Zb[j * NN2 + i] * lam[j];
    float v = (float)acc;
    xm[i] = fminf(fmaxf(v, 0.f), 1.f);
  }
  __syncthreads();

  // output row i = softmax over j of 1000 * xm[j*36+i]
  if (tid < NNODE) {
    int i = tid;
    float m = -1e30f;
    for (int j = 0; j < NNODE; ++j) m = fmaxf(m, 1000.f * xm[j * NNODE + i]);
    float sum = 0.f;
    for (int j = 0; j < NNODE; ++j) sum += expf(1000.f * xm[j * NNODE + i] - m);
    float inv = 1.f / sum;
    for (int j = 0; j < NNODE; ++j)
      out[(size_t)b * NN2 + i * NNODE + j] = expf(1000.f * xm[j * NNODE + i] - m) * inv;
  }
}

// ---------------------------------------------------------------------------
extern "C" void kernel_launch(void* const* d_in, const int* in_sizes, int n_in,
                              void* d_out, int out_size, void* d_ws, size_t ws_size,
                              hipStream_t stream) {
  (void)in_sizes; (void)n_in; (void)out_size; (void)ws_size;
  const float* emb1 = (const float*)d_in[0];
  const float* emb2 = (const float*)d_in[1];
  const float* Wcg  = (const float*)d_in[2];
  const float* bcg  = (const float*)d_in[3];
  float* out = (float*)d_out;

  char* ws = (char*)d_ws;
  float*  PT = (float*) (ws);                          // 8*1296 f32    = 41472 B
  float*  Z  = (float*) (ws + 41472);                  // 8*72*1296 f32 = 2985984 B
  double* Y  = (double*)(ws + 41472 + 2985984);        // 8*1296 f64    = 82944 B

  hipLaunchKernelGGL(k_feat_p,    dim3(NB),      dim3(256), 0, stream, emb1, emb2, Wcg, bcg, PT);
  hipLaunchKernelGGL(k_cg,        dim3(NB * 73), dim3(256), 0, stream, PT, Z, Y);
  hipLaunchKernelGGL(k_solve_out, dim3(NB),      dim3(256), 0, stream, Z, Y, out);
}

// Round 7
// 241.261 us; speedup vs baseline: 1.1447x; 1.1447x over previous
//
#include <hip/hip_runtime.h>
#include <math.h>

// Problem constants (B=8, N=36, D=64)
#define NB    8
#define NNODE 36
#define NN2   1296     // 36*36
#define ND    64
#define NC    72       // 2*N constraints
#define KDIAG 1225.0   // (N-1)^2
#define EPSK  1e-5
#define CGMAX 32
#define PERTHREAD 6    // ceil(1296/256)

// ---------------------------------------------------------------------------
// Block-wide fp64 sum reduction (256 threads = 4 waves of 64)
// ---------------------------------------------------------------------------
__device__ __forceinline__ double blk_reduce(double v, double* red, double* out) {
#pragma unroll
  for (int off = 32; off > 0; off >>= 1) v += __shfl_down(v, off);
  if ((threadIdx.x & 63) == 0) red[threadIdx.x >> 6] = v;
  __syncthreads();
  if (threadIdx.x == 0) *out = red[0] + red[1] + red[2] + red[3];
  __syncthreads();
  return *out;
}

// ---------------------------------------------------------------------------
// Kernel 1: normalize over node axis, linear (W_cg,b_cg), relu, then
// PT[b][t][s] = Mp[b][s][t] = h1[b,s,:]·h2[b,t,:]
// PT flat (t-major) is simultaneously the KKT primal rhs Mpp.
// ---------------------------------------------------------------------------
__global__ __launch_bounds__(256) void k_feat_p(const float* __restrict__ emb1,
                                                const float* __restrict__ emb2,
                                                const float* __restrict__ Wcg,
                                                const float* __restrict__ bcg,
                                                float* __restrict__ PT) {
  const int b = blockIdx.x;
  __shared__ float e1[NNODE * ND], e2[NNODE * ND];
  __shared__ float h1[NNODE * ND], h2[NNODE * ND];
  __shared__ float Ws[ND * ND];
  __shared__ float nrm1[ND], nrm2[ND];
  const int tid = threadIdx.x;

  for (int i = tid; i < NNODE * ND; i += 256) {
    e1[i] = emb1[b * NNODE * ND + i];
    e2[i] = emb2[b * NNODE * ND + i];
  }
  for (int i = tid; i < ND * ND; i += 256) Ws[i] = Wcg[i];
  __syncthreads();

  // per-(b,d) L2 norm over the 36 nodes, clipped at 1e-12 (ref: clip(norm,1e-12))
  if (tid < ND) {
    float s = 0.f;
    for (int n = 0; n < NNODE; ++n) { float v = e1[n * ND + tid]; s += v * v; }
    nrm1[tid] = fmaxf(sqrtf(s), 1e-12f);
  } else if (tid < 2 * ND) {
    int d = tid - ND;
    float s = 0.f;
    for (int n = 0; n < NNODE; ++n) { float v = e2[n * ND + d]; s += v * v; }
    nrm2[d] = fmaxf(sqrtf(s), 1e-12f);
  }
  __syncthreads();

  for (int i = tid; i < NNODE * ND; i += 256) {
    int d = i & (ND - 1);
    e1[i] /= nrm1[d];
    e2[i] /= nrm2[d];
  }
  __syncthreads();

  // h[n][i] = relu( sum_d e[n][d] * W[i][d] + b[i] )
  for (int o = tid; o < NNODE * ND; o += 256) {
    int n = o >> 6, i = o & (ND - 1);
    float a1 = bcg[i], a2 = bcg[i];
    for (int d = 0; d < ND; ++d) {
      float w = Ws[i * ND + d];
      a1 += e1[n * ND + d] * w;
      a2 += e2[n * ND + d] * w;
    }
    h1[o] = fmaxf(a1, 0.f);
    h2[o] = fmaxf(a2, 0.f);
  }
  __syncthreads();

  // PT[t][s] = sum_d h1[s][d]*h2[t][d]
  for (int o = tid; o < NN2; o += 256) {
    int t = o / NNODE, s = o % NNODE;
    float a = 0.f;
    for (int d = 0; d < ND; ++d) a += h1[s * ND + d] * h2[t * ND + d];
    PT[b * NN2 + o] = a;
  }
}

// ---------------------------------------------------------------------------
// Kernel 2: one workgroup per (batch, rhs) — fp64 CG on Q = 1225*I - M,
// with O(n^2) structured matvec (inclusion-exclusion over the delta masks):
//   (Mx)[t][s] = 0.5*( PT[t][s]*(tot - R[t] - C[s] + x[t][s])
//                     + (Wtot - WR[t] - WC[s] + PT[t][s]*x[t][s]) )
//   where W = PT .* x,  R/C = row/col sums of x (row = first flat index).
// Epilogue: each block also emits A*x (its column of the Schur matrix
// S = A Q^-1 A^T, fp64) into Scols[b][rid][0..71]; the rid==72 block emits
// the Schur rhs A*y - 1 instead. This removes the strided S-assembly pass
// that dominated the old k_solve_out (175 us of 276 total, round-5 counters).
// rid==72 -> rhs = PT (primal rhs), store fp64 into Y
// rid<36  -> rhs = (second idx == rid) indicator (A1 row);
// rid in [36,72) -> (first idx == rid-36) indicator (A2 row).
// ---------------------------------------------------------------------------
__global__ __launch_bounds__(256) void k_cg(const float* __restrict__ PT,
                                            float* __restrict__ Z,
                                            double* __restrict__ Y,
                                            double* __restrict__ Scols) {
  const int b = blockIdx.x / 73;
  const int rid = blockIdx.x % 73;
  const int tid = threadIdx.x;

  __shared__ float pt[NN2];
  __shared__ double pv[NN2];
  __shared__ double R[NNODE], C[NNODE], WR[NNODE], WC[NNODE];
  __shared__ double totW[2];  // [0]=tot(pv), [1]=tot(pt.*pv)
  __shared__ double red[4], s_pap, s_rr;

  double xl[PERTHREAD], rl[PERTHREAD], al[PERTHREAD];

  for (int i = tid; i < NN2; i += 256) pt[i] = PT[b * NN2 + i];
  __syncthreads();

#pragma unroll
  for (int k = 0; k < PERTHREAD; ++k) {
    int i = tid + 256 * k;
    if (i >= NN2) break;
    int t = i / NNODE, s = i % NNODE;
    double rhs;
    if (rid == 72)      rhs = (double)pt[i];
    else if (rid < 36)  rhs = (s == rid) ? 1.0 : 0.0;
    else                rhs = (t == rid - 36) ? 1.0 : 0.0;
    xl[k] = 0.0; rl[k] = rhs; pv[i] = rhs;
  }
  __syncthreads();

  double loc = 0.0;
#pragma unroll
  for (int k = 0; k < PERTHREAD; ++k) {
    int i = tid + 256 * k;
    if (i < NN2) loc += rl[k] * rl[k];
  }
  double rr = blk_reduce(loc, red, &s_rr);
  const double rr0 = rr;

  for (int it = 0; it < CGMAX; ++it) {
    // ---- row/col sums of pv and W = pt.*pv ----
    if (tid < NNODE) {
      double r0 = 0.0, wr0 = 0.0;
      for (int s = 0; s < NNODE; ++s) {
        double v = pv[tid * NNODE + s];
        r0 += v; wr0 += (double)pt[tid * NNODE + s] * v;
      }
      R[tid] = r0; WR[tid] = wr0;
    } else if (tid < 2 * NNODE) {
      int s = tid - NNODE;
      double c0 = 0.0, wc0 = 0.0;
      for (int t = 0; t < NNODE; ++t) {
        double v = pv[t * NNODE + s];
        c0 += v; wc0 += (double)pt[t * NNODE + s] * v;
      }
      C[s] = c0; WC[s] = wc0;
    }
    __syncthreads();
    if (tid == 0) {
      double tt = 0.0, wt = 0.0;
      for (int t = 0; t < NNODE; ++t) { tt += R[t]; wt += WR[t]; }
      totW[0] = tt; totW[1] = wt;
    }
    __syncthreads();

    // ---- ap = Q*pv (registers), pap = pv.ap ----
    double locpap = 0.0;
#pragma unroll
    for (int k = 0; k < PERTHREAD; ++k) {
      int i = tid + 256 * k;
      if (i >= NN2) break;
      int t = i / NNODE, s = i % NNODE;
      double pval = pv[i], ptv = (double)pt[i];
      double sig1 = totW[0] - R[t] - C[s] + pval;
      double sig2 = totW[1] - WR[t] - WC[s] + ptv * pval;
      double q = KDIAG * pval - 0.5 * (ptv * sig1 + sig2);
      al[k] = q;
      locpap += pval * q;
    }
    double pap = blk_reduce(locpap, red, &s_pap);
    double alpha = rr / pap;

    double locrr = 0.0;
#pragma unroll
    for (int k = 0; k < PERTHREAD; ++k) {
      int i = tid + 256 * k;
      if (i >= NN2) break;
      xl[k] += alpha * pv[i];
      double rn = rl[k] - alpha * al[k];
      rl[k] = rn;
      locrr += rn * rn;
    }
    double rrn = blk_reduce(locrr, red, &s_rr);
    double beta = rrn / rr;
    rr = rrn;
    // rel. residual 1e-9: plenty vs the reference's own fp32-LU noise, and
    // S-assembly error stays ~1e-10 << eps pivot 1e-5. Exit is block-uniform.
    if (rr < 1e-18 * rr0 || rr < 1e-30) break;
#pragma unroll
    for (int k = 0; k < PERTHREAD; ++k) {
      int i = tid + 256 * k;
      if (i < NN2) pv[i] = rl[k] + beta * pv[i];
    }
    __syncthreads();
  }

  // ---- store solution ----
  if (rid == 72) {
#pragma unroll
    for (int k = 0; k < PERTHREAD; ++k) {
      int i = tid + 256 * k;
      if (i < NN2) Y[b * NN2 + i] = xl[k];
    }
  } else {
#pragma unroll
    for (int k = 0; k < PERTHREAD; ++k) {
      int i = tid + 256 * k;
      if (i < NN2) Z[(b * NC + rid) * NN2 + i] = (float)xl[k];
    }
  }

  // ---- epilogue: A*x -> Schur column (or Schur rhs A*y - 1 for rid==72) ----
  __syncthreads();   // all threads done reading pv in the CG loop
#pragma unroll
  for (int k = 0; k < PERTHREAD; ++k) {
    int i = tid + 256 * k;
    if (i < NN2) pv[i] = xl[k];
  }
  __syncthreads();
  if (tid < NNODE) {                 // S rows 36..71: first-index (row) sums
    double r0 = 0.0;
    for (int s = 0; s < NNODE; ++s) r0 += pv[tid * NNODE + s];
    if (rid == 72) r0 -= 1.0;
    Scols[((size_t)b * 73 + rid) * NC + NNODE + tid] = r0;
  } else if (tid < 2 * NNODE) {      // S rows 0..35: second-index (col) sums
    int s = tid - NNODE;
    double c0 = 0.0;
    for (int t = 0; t < NNODE; ++t) c0 += pv[t * NNODE + s];
    if (rid == 72) c0 -= 1.0;
    Scols[((size_t)b * 73 + rid) * NC + s] = c0;
  }
}

// ---------------------------------------------------------------------------
// Kernel 3: per batch, S (prebuilt columns) + eps*I, rhs = A*y - 1 (prebuilt),
// fp64 Cholesky + triangular solves -> LAM.
// ---------------------------------------------------------------------------
__global__ __launch_bounds__(256) void k_chol(const double* __restrict__ Scols,
                                              double* __restrict__ LAM) {
  const int b = blockIdx.x;
  const int tid = threadIdx.x;
  __shared__ double S[NC * NC];
  __shared__ double lam[NC];

  for (int o = tid; o < NC * NC; o += 256) {
    int i = o / NC, j = o % NC;
    double v = Scols[((size_t)b * 73 + j) * NC + i];  // S[i][j] (symmetric)
    if (i == j) v += EPSK;
    S[o] = v;
  }
  if (tid < NC) lam[tid] = Scols[((size_t)b * 73 + 72) * NC + tid];
  __syncthreads();

  // Cholesky (lower), in place
  for (int j = 0; j < NC; ++j) {
    if (tid == 0) {
      double d = S[j * NC + j];
      for (int k = 0; k < j; ++k) d -= S[j * NC + k] * S[j * NC + k];
      S[j * NC + j] = sqrt(d);
    }
    __syncthreads();
    for (int i = j + 1 + tid; i < NC; i += 256) {
      double v = S[i * NC + j];
      for (int k = 0; k < j; ++k) v -= S[i * NC + k] * S[j * NC + k];
      S[i * NC + j] = v / S[j * NC + j];
    }
    __syncthreads();
  }
  // forward: L u = rhs
  for (int j = 0; j < NC; ++j) {
    if (tid == 0) lam[j] = lam[j] / S[j * NC + j];
    __syncthreads();
    for (int i = j + 1 + tid; i < NC; i += 256) lam[i] -= S[i * NC + j] * lam[j];
    __syncthreads();
  }
  // backward: L^T lam = u
  for (int j = NC - 1; j >= 0; --j) {
    if (tid == 0) lam[j] = lam[j] / S[j * NC + j];
    __syncthreads();
    if (tid < j) lam[tid] -= S[j * NC + tid] * lam[j];
    __syncthreads();
  }
  if (tid < NC) LAM[b * NC + tid] = lam[tid];
}

// ---------------------------------------------------------------------------
// Kernel 4: x = y - Z*lambda (coalesced Z reads), clamp [0,1],
// out[b][i][j] = softmax_j(1000 * x[j][i]).
// Per-row max/denominator on 36 threads; all 256 threads write the output.
// ---------------------------------------------------------------------------
__global__ __launch_bounds__(256) void k_xout(const float* __restrict__ Z,
                                              const double* __restrict__ Y,
                                              const double* __restrict__ LAM,
                                              float* __restrict__ out) {
  const int b = blockIdx.x;
  const int tid = threadIdx.x;
  __shared__ double lam[NC];
  __shared__ float xm[NN2];
  __shared__ float mrow[NNODE], irow[NNODE];

  if (tid < NC) lam[tid] = LAM[b * NC + tid];
  __syncthreads();

  const float* Zb = Z + (size_t)b * NC * NN2;
  const double* yb = Y + (size_t)b * NN2;

  // x = y - Z*lambda: thread -> element i (consecutive => coalesced over j)
  for (int i = tid; i < NN2; i += 256) {
    double acc = yb[i];
#pragma unroll 8
    for (int j = 0; j < NC; ++j) acc -= (double)Zb[j * NN2 + i] * lam[j];
    float v = (float)acc;
    xm[i] = fminf(fmaxf(v, 0.f), 1.f);
  }
  __syncthreads();

  // per-output-row i: max and softmax denominator over j (column i of xm)
  if (tid < NNODE) {
    float m = -1e30f;
    for (int j = 0; j < NNODE; ++j) m = fmaxf(m, xm[j * NNODE + tid]);
    float sum = 0.f;
    for (int j = 0; j < NNODE; ++j) sum += expf(1000.f * (xm[j * NNODE + tid] - m));
    mrow[tid] = m;
    irow[tid] = 1.f / sum;
  }
  __syncthreads();

  for (int o = tid; o < NN2; o += 256) {
    int i = o / NNODE, j = o % NNODE;
    out[(size_t)b * NN2 + o] = expf(1000.f * (xm[j * NNODE + i] - mrow[i])) * irow[i];
  }
}

// ---------------------------------------------------------------------------
extern "C" void kernel_launch(void* const* d_in, const int* in_sizes, int n_in,
                              void* d_out, int out_size, void* d_ws, size_t ws_size,
                              hipStream_t stream) {
  (void)in_sizes; (void)n_in; (void)out_size; (void)ws_size;
  const float* emb1 = (const float*)d_in[0];
  const float* emb2 = (const float*)d_in[1];
  const float* Wcg  = (const float*)d_in[2];
  const float* bcg  = (const float*)d_in[3];
  float* out = (float*)d_out;

  char* ws = (char*)d_ws;
  float*  PT    = (float*) (ws);                 // 8*1296 f32          = 41472 B
  float*  Z     = (float*) (ws + 41472);         // 8*72*1296 f32       = 2985984 B
  double* Y     = (double*)(ws + 3027456);       // 8*1296 f64          = 82944 B
  double* Scols = (double*)(ws + 3110400);       // 8*73*72 f64         = 336384 B
  double* LAM   = (double*)(ws + 3446784);       // 8*72 f64            = 4608 B

  hipLaunchKernelGGL(k_feat_p, dim3(NB),      dim3(256), 0, stream, emb1, emb2, Wcg, bcg, PT);
  hipLaunchKernelGGL(k_cg,     dim3(NB * 73), dim3(256), 0, stream, PT, Z, Y, Scols);
  hipLaunchKernelGGL(k_chol,   dim3(NB),      dim3(256), 0, stream, Scols, LAM);
  hipLaunchKernelGGL(k_xout,   dim3(NB),      dim3(256), 0, stream, Z, Y, LAM, out);
}